// Round 5
// baseline (1379.727 us; speedup 1.0000x reference)
//
#include <hip/hip_runtime.h>
#include <hip/hip_bf16.h>

#define T_DIM 4096
#define B_DIM 4

typedef unsigned short u16;
typedef __attribute__((ext_vector_type(4))) short s16x4;
typedef __attribute__((ext_vector_type(8))) short short8;
typedef __attribute__((ext_vector_type(8))) __bf16 bf16x8;
typedef __attribute__((ext_vector_type(4))) float f32x4;

static __device__ __forceinline__ u16 f2bf(float f) {
    union { float f; unsigned int u; } v; v.f = f;
    unsigned int u = v.u;
    u += 0x7FFFu + ((u >> 16) & 1u);   // RNE
    return (u16)(u >> 16);
}

static __device__ __forceinline__ f32x4 mfma_k32(short8 a, short8 b, f32x4 c) {
    return __builtin_amdgcn_mfma_f32_16x16x32_bf16(
        __builtin_bit_cast(bf16x8, a), __builtin_bit_cast(bf16x8, b), c, 0, 0, 0);
}
static __device__ __forceinline__ f32x4 mfma_k16(s16x4 a, s16x4 b, f32x4 c) {
    return __builtin_amdgcn_mfma_f32_16x16x16bf16_1k(a, b, c, 0, 0, 0);
}

// ---------------------------------------------------------------------------
// Kernel 0: transpose + convert weights to bf16 W^T[n][k]
// ---------------------------------------------------------------------------
__global__ __launch_bounds__(256) void wtrans_kernel(
    const float* __restrict__ Wq, const float* __restrict__ Wk,
    const float* __restrict__ Wv, u16* __restrict__ wT) {
    int idx = blockIdx.x * 256 + threadIdx.x;
    int w   = idx >> 16;
    int rem = idx & 65535;
    int k   = rem >> 8;
    int n   = rem & 255;
    const float* W = (w == 0) ? Wq : (w == 1) ? Wk : Wv;
    wT[w * 65536 + n * 256 + k] = f2bf(W[k * 256 + n]);
}

// ---------------------------------------------------------------------------
// Kernel 1: projection GEMM -> FRAGMENT-PACKED outputs.
//  qf/kf layout (u16): [b][tile=t/16][kc=0..7][lane][e=0..7]
//      value = P[b][tile*16 + (lane&15)][kc*32 + (lane>>4)*8 + e]
//  vf layout (u16):    [b][jt=t/64][nf=0..15][c=0..3][lane][e=0..3]
//      value = V[b][jt*64 + 16*c + 4*(lane>>4) + e][nf*16 + (lane&15)]
// Every attn-kernel load becomes lane-contiguous.
// ---------------------------------------------------------------------------
__global__ __launch_bounds__(256, 4) void proj_kernel(
    const float* __restrict__ X, const u16* __restrict__ wT,
    u16* __restrict__ qf, u16* __restrict__ kf, u16* __restrict__ vfw) {
    const int r0  = blockIdx.x * 16;
    const int wid = threadIdx.x >> 6, lane = threadIdx.x & 63;
    const int lr  = lane & 15, lg = lane >> 4;

    short8 af[8];
    const float* xrow = X + (size_t)(r0 + lr) * 256 + lg * 8;
#pragma unroll
    for (int kc = 0; kc < 8; ++kc) {
        f32x4 xa = *(const f32x4*)(xrow + kc * 32);
        f32x4 xb = *(const f32x4*)(xrow + kc * 32 + 4);
        union { u16 u[8]; short8 v; } t;
#pragma unroll
        for (int e = 0; e < 4; ++e) { t.u[e] = f2bf(xa[e]); t.u[4 + e] = f2bf(xb[e]); }
        af[kc] = t.v;
    }

    for (int w = 0; w < 3; ++w) {
        f32x4 acc[4];
#pragma unroll
        for (int nf = 0; nf < 4; ++nf) acc[nf] = (f32x4){0.f,0.f,0.f,0.f};
        const u16* wbase = wT + w * 65536 + (size_t)(16 * (4 * wid) + lr) * 256 + lg * 8;
#pragma unroll
        for (int kc = 0; kc < 8; ++kc)
#pragma unroll
            for (int nf = 0; nf < 4; ++nf) {
                short8 bfv = *(const short8*)(wbase + nf * 16 * 256 + kc * 32);
                acc[nf] = mfma_k32(af[kc], bfv, acc[nf]);
            }
#pragma unroll
        for (int nf = 0; nf < 4; ++nf)
#pragma unroll
            for (int r = 0; r < 4; ++r) {
                int rg = r0 + 4 * lg + r;
                int t  = rg >> 2, bb = rg & 3;           // X rows are (t, b)
                int d  = 16 * (4 * wid + nf) + lr;
                u16 val = f2bf(acc[nf][r]);
                if (w < 2) {
                    int tile = t >> 4, lrq = t & 15;
                    int kc = d >> 5, lgq = (d >> 3) & 3, e = d & 7;
                    size_t idx = ((((size_t)bb * 256 + tile) * 8 + kc) * 64
                                  + lrq + 16 * lgq) * 8 + e;
                    if (w == 0) qf[idx] = val; else kf[idx] = val;
                } else {
                    int jt = t >> 6, c = (t >> 4) & 3;
                    int lgv = (t >> 2) & 3, ev = t & 3;
                    int nfv = d >> 4, lrv = d & 15;
                    size_t idx = (((((size_t)bb * 64 + jt) * 16 + nfv) * 4 + c) * 64
                                  + lrv + 16 * lgv) * 4 + ev;
                    vfw[idx] = val;
                }
            }
    }
}

// ---------------------------------------------------------------------------
// Kernel 2: fused causal attention. ONE WAVE per block; wave owns 16 query
// rows and the full 64-wide j-tile -> 4 independent QK^T MFMA chains, no LDS,
// no barriers, no atomics. Sweep 1: row sums (2 shfl_xor). Sweep 2: attn
// write (f32x4 nontemporal) + PV via 16x16x16 (P regs are the A-frag).
// ---------------------------------------------------------------------------
__global__ __launch_bounds__(64, 2) void attn_kernel(
    const u16* __restrict__ qf, const u16* __restrict__ kf,
    const u16* __restrict__ vfw, float* __restrict__ out) {
    const int blk = blockIdx.x;
    const int xcd = blk & 7, idx = blk >> 3;
    const int b = xcd >> 1, par = xcd & 1;     // one b per XCD pair (K/V L2-resident)
    const int i_tile = 2 * idx + par;          // 0..255
    const int i0 = i_tile * 16;

    const int lane = threadIdx.x;
    const int lr = lane & 15, lg = lane >> 4;

    float* attnO = out + (size_t)T_DIM * B_DIM * 256 + (size_t)b * T_DIM * T_DIM;
    const int irow = i0 + lr;

    // Q fragments (lane-contiguous)
    short8 q8[8];
    const short8* qp = (const short8*)(qf + (((size_t)b * 256 + i_tile) * 8) * 512);
#pragma unroll
    for (int kc = 0; kc < 8; ++kc) q8[kc] = qp[kc * 64 + lane];

    const int numJT = i_tile / 4 + 1;

    // ---- sweep 1: row sums of exp(S) ----
    float rs = 0.f;
    for (int jt = 0; jt < numJT; ++jt) {
        const short8* kp = (const short8*)(kf + (((size_t)b * 256 + jt * 4) * 8) * 512);
        f32x4 a[4];
#pragma unroll
        for (int c = 0; c < 4; ++c) a[c] = (f32x4){0.f,0.f,0.f,0.f};
#pragma unroll
        for (int kc = 0; kc < 8; ++kc)
#pragma unroll
            for (int c = 0; c < 4; ++c)
                a[c] = mfma_k32(kp[(c * 8 + kc) * 64 + lane], q8[kc], a[c]);
#pragma unroll
        for (int c = 0; c < 4; ++c)
#pragma unroll
            for (int r = 0; r < 4; ++r) {
                int j = jt * 64 + 16 * c + 4 * lg + r;
                rs += (j <= irow) ? __expf(a[c][r] * 0.0625f) : 0.f;
            }
    }
    rs += __shfl_xor(rs, 16, 64);
    rs += __shfl_xor(rs, 32, 64);
    const float inv = 1.0f / rs;

    // ---- sweep 2: attn write + PV ----
    f32x4 oacc[16];
#pragma unroll
    for (int nf = 0; nf < 16; ++nf) oacc[nf] = (f32x4){0.f,0.f,0.f,0.f};

    for (int jt = 0; jt < numJT; ++jt) {
        const short8* kp = (const short8*)(kf + (((size_t)b * 256 + jt * 4) * 8) * 512);
        f32x4 a[4];
#pragma unroll
        for (int c = 0; c < 4; ++c) a[c] = (f32x4){0.f,0.f,0.f,0.f};
#pragma unroll
        for (int kc = 0; kc < 8; ++kc)
#pragma unroll
            for (int c = 0; c < 4; ++c)
                a[c] = mfma_k32(kp[(c * 8 + kc) * 64 + lane], q8[kc], a[c]);

        s16x4 pk[4];
#pragma unroll
        for (int c = 0; c < 4; ++c) {
            f32x4 p;
#pragma unroll
            for (int r = 0; r < 4; ++r) {
                int j = jt * 64 + 16 * c + 4 * lg + r;
                p[r] = (j <= irow) ? __expf(a[c][r] * 0.0625f) * inv : 0.f;
            }
            __builtin_nontemporal_store(p,
                (f32x4*)(attnO + (size_t)irow * T_DIM + jt * 64 + 16 * c + 4 * lg));
            union { u16 u[4]; s16x4 v; } t;
#pragma unroll
            for (int r = 0; r < 4; ++r) t.u[r] = f2bf(p[r]);
            pk[c] = t.v;
        }
#pragma unroll
        for (int nf = 0; nf < 16; ++nf) {
            const s16x4* vp = (const s16x4*)(vfw +
                ((((size_t)b * 64 + jt) * 16 + nf) * 4) * 256);
#pragma unroll
            for (int c = 0; c < 4; ++c)
                oacc[nf] = mfma_k16(pk[c], vp[c * 64 + lane], oacc[nf]);
        }
    }

    // O store -> results[t][b][d]  (oacc[nf][r] = O[i0+4lg+r][16nf+lr])
#pragma unroll
    for (int nf = 0; nf < 16; ++nf)
#pragma unroll
        for (int r = 0; r < 4; ++r)
            out[((size_t)(i0 + 4 * lg + r) * B_DIM + b) * 256 + 16 * nf + lr] = oacc[nf][r];

    // zero-fill strict upper triangle beyond computed tiles
    const int z0 = numJT * 64;
    if (z0 < T_DIM) {
        const int n4 = (T_DIM - z0) >> 2;
        for (int rr = 0; rr < 16; ++rr) {
            f32x4* rowp = (f32x4*)(attnO + (size_t)(i0 + rr) * T_DIM + z0);
            for (int c = lane; c < n4; c += 64) {
                f32x4 z = {0.f, 0.f, 0.f, 0.f};
                __builtin_nontemporal_store(z, rowp + c);
            }
        }
    }
}

// ---------------------------------------------------------------------------
extern "C" void kernel_launch(void* const* d_in, const int* in_sizes, int n_in,
                              void* d_out, int out_size, void* d_ws, size_t ws_size,
                              hipStream_t stream) {
    (void)in_sizes; (void)n_in; (void)out_size; (void)ws_size;
    const float* X  = (const float*)d_in[0];
    const float* Wq = (const float*)d_in[1];
    const float* Wk = (const float*)d_in[2];
    const float* Wv = (const float*)d_in[3];
    float* out = (float*)d_out;

    char* ws = (char*)d_ws;
    u16* qf  = (u16*)(ws);                                  // 8 MB
    u16* kf  = (u16*)(ws + (size_t)8  * 1024 * 1024);       // 8 MB
    u16* vfw = (u16*)(ws + (size_t)16 * 1024 * 1024);       // 8 MB
    u16* wT  = (u16*)(ws + (size_t)24 * 1024 * 1024);       // 384 KB

    wtrans_kernel<<<dim3(768), dim3(256), 0, stream>>>(Wq, Wk, Wv, wT);
    proj_kernel<<<dim3(1024), dim3(256), 0, stream>>>(X, wT, qf, kf, vfw);
    attn_kernel<<<dim3(1024), dim3(64), 0, stream>>>(qf, kf, vfw, out);
}

// Round 7
// 449.876 us; speedup vs baseline: 3.0669x; 3.0669x over previous
//
#include <hip/hip_runtime.h>
#include <hip/hip_bf16.h>

#define T_DIM 4096
#define B_DIM 4

typedef unsigned short u16;
typedef __attribute__((ext_vector_type(4))) short s16x4;
typedef __attribute__((ext_vector_type(8))) short short8;
typedef __attribute__((ext_vector_type(8))) __bf16 bf16x8;
typedef __attribute__((ext_vector_type(4))) float f32x4;

static __device__ __forceinline__ u16 f2bf(float f) {
    union { float f; unsigned int u; } v; v.f = f;
    unsigned int u = v.u;
    u += 0x7FFFu + ((u >> 16) & 1u);   // RNE
    return (u16)(u >> 16);
}

static __device__ __forceinline__ f32x4 mfma_k32(short8 a, short8 b, f32x4 c) {
    return __builtin_amdgcn_mfma_f32_16x16x32_bf16(
        __builtin_bit_cast(bf16x8, a), __builtin_bit_cast(bf16x8, b), c, 0, 0, 0);
}
static __device__ __forceinline__ f32x4 mfma_k16(s16x4 a, s16x4 b, f32x4 c) {
    return __builtin_amdgcn_mfma_f32_16x16x16bf16_1k(a, b, c, 0, 0, 0);
}

// ---------------------------------------------------------------------------
// Kernel 0: transpose + convert weights to bf16 W^T[n][k]
// ---------------------------------------------------------------------------
__global__ __launch_bounds__(256) void wtrans_kernel(
    const float* __restrict__ Wq, const float* __restrict__ Wk,
    const float* __restrict__ Wv, u16* __restrict__ wT) {
    int idx = blockIdx.x * 256 + threadIdx.x;
    int w   = idx >> 16;
    int rem = idx & 65535;
    int k   = rem >> 8;
    int n   = rem & 255;
    const float* W = (w == 0) ? Wq : (w == 1) ? Wk : Wv;
    wT[w * 65536 + n * 256 + k] = f2bf(W[k * 256 + n]);
}

// ---------------------------------------------------------------------------
// Kernel 1: projection GEMM -> FRAGMENT-PACKED outputs (validated in R4).
//  qf/kf (u16): [b][tile=t/16][kc=0..7][lane][e=0..7]
//      = P[b][tile*16 + (lane&15)][kc*32 + (lane>>4)*8 + e]
//  vf  (u16): [b][jt=t/64][nf=0..15][c=0..3][lane][e=0..3]
//      = V[b][jt*64 + 16*c + 4*(lane>>4) + e][nf*16 + (lane&15)]
// ---------------------------------------------------------------------------
__global__ __launch_bounds__(256, 4) void proj_kernel(
    const float* __restrict__ X, const u16* __restrict__ wT,
    u16* __restrict__ qf, u16* __restrict__ kf, u16* __restrict__ vfw) {
    const int r0  = blockIdx.x * 16;
    const int wid = threadIdx.x >> 6, lane = threadIdx.x & 63;
    const int lr  = lane & 15, lg = lane >> 4;

    short8 af[8];
    const float* xrow = X + (size_t)(r0 + lr) * 256 + lg * 8;
#pragma unroll
    for (int kc = 0; kc < 8; ++kc) {
        f32x4 xa = *(const f32x4*)(xrow + kc * 32);
        f32x4 xb = *(const f32x4*)(xrow + kc * 32 + 4);
        union { u16 u[8]; short8 v; } t;
#pragma unroll
        for (int e = 0; e < 4; ++e) { t.u[e] = f2bf(xa[e]); t.u[4 + e] = f2bf(xb[e]); }
        af[kc] = t.v;
    }

    for (int w = 0; w < 3; ++w) {
        f32x4 acc[4];
#pragma unroll
        for (int nf = 0; nf < 4; ++nf) acc[nf] = (f32x4){0.f,0.f,0.f,0.f};
        const u16* wbase = wT + w * 65536 + (size_t)(16 * (4 * wid) + lr) * 256 + lg * 8;
#pragma unroll
        for (int kc = 0; kc < 8; ++kc)
#pragma unroll
            for (int nf = 0; nf < 4; ++nf) {
                short8 bfv = *(const short8*)(wbase + nf * 16 * 256 + kc * 32);
                acc[nf] = mfma_k32(af[kc], bfv, acc[nf]);
            }
#pragma unroll
        for (int nf = 0; nf < 4; ++nf)
#pragma unroll
            for (int r = 0; r < 4; ++r) {
                int rg = r0 + 4 * lg + r;
                int t  = rg >> 2, bb = rg & 3;           // X rows are (t, b)
                int d  = 16 * (4 * wid + nf) + lr;
                u16 val = f2bf(acc[nf][r]);
                if (w < 2) {
                    int tile = t >> 4, lrq = t & 15;
                    int kc = d >> 5, lgq = (d >> 3) & 3, e = d & 7;
                    size_t idx = ((((size_t)bb * 256 + tile) * 8 + kc) * 64
                                  + lrq + 16 * lgq) * 8 + e;
                    if (w == 0) qf[idx] = val; else kf[idx] = val;
                } else {
                    int jt = t >> 6, c = (t >> 4) & 3;
                    int lgv = (t >> 2) & 3, ev = t & 3;
                    int nfv = d >> 4, lrv = d & 15;
                    size_t idx = (((((size_t)bb * 64 + jt) * 16 + nfv) * 4 + c) * 64
                                  + lrv + 16 * lgv) * 4 + ev;
                    vfw[idx] = val;
                }
            }
    }
}

// ---------------------------------------------------------------------------
// Kernel 2: fused causal attention. Block = 4 waves on ONE 16-row i_tile;
// j-tiles strided across waves (jt = wid, wid+4, ...). Each wave: 4
// independent QK^T chains, lane-local P, barrier-free j-loop. Row sums
// combined via one LDS-atomic pass; O partials combined via LDS at the end.
// ---------------------------------------------------------------------------
__global__ __launch_bounds__(256, 2) void attn_kernel(
    const u16* __restrict__ qf, const u16* __restrict__ kf,
    const u16* __restrict__ vfw, float* __restrict__ out) {
    __shared__ float l_sm[16];
    __shared__ float O_sm[16 * 264];

    const int blk = blockIdx.x;
    const int xcd = blk & 7, idx = blk >> 3;
    const int b = xcd >> 1, par = xcd & 1;       // one b per XCD pair
    const int i_tile = 2 * (127 - idx) + par;    // heavy tiles first
    const int i0 = i_tile * 16;

    const int tid = threadIdx.x;
    const int wid = tid >> 6, lane = tid & 63;
    const int lr = lane & 15, lg = lane >> 4;

    float* attnO = out + (size_t)T_DIM * B_DIM * 256 + (size_t)b * T_DIM * T_DIM;
    const int irow = i0 + lr;

    // Q fragments (lane-contiguous), shared by all waves
    short8 q8[8];
    const short8* qp = (const short8*)(qf + (((size_t)b * 256 + i_tile) * 8) * 512);
#pragma unroll
    for (int kc = 0; kc < 8; ++kc) q8[kc] = qp[kc * 64 + lane];

    if (tid < 16) l_sm[tid] = 0.f;
    __syncthreads();

    const int numJT = i_tile / 4 + 1;

    // ---- sweep 1: partial row sums of exp(S), this wave's j-tiles ----
    float rs = 0.f;
    for (int jt = wid; jt < numJT; jt += 4) {
        const short8* kp = (const short8*)(kf + (((size_t)b * 256 + jt * 4) * 8) * 512);
        f32x4 a[4];
#pragma unroll
        for (int c = 0; c < 4; ++c) a[c] = (f32x4){0.f,0.f,0.f,0.f};
#pragma unroll
        for (int kc = 0; kc < 8; ++kc)
#pragma unroll
            for (int c = 0; c < 4; ++c)
                a[c] = mfma_k32(kp[(c * 8 + kc) * 64 + lane], q8[kc], a[c]);
#pragma unroll
        for (int c = 0; c < 4; ++c)
#pragma unroll
            for (int r = 0; r < 4; ++r) {
                int j = jt * 64 + 16 * c + 4 * lg + r;
                rs += (j <= irow) ? __expf(a[c][r] * 0.0625f) : 0.f;
            }
    }
    rs += __shfl_xor(rs, 16, 64);
    rs += __shfl_xor(rs, 32, 64);
    if (lane < 16) atomicAdd(&l_sm[lr], rs);
    __syncthreads();
    const float inv = 1.0f / l_sm[lr];

    // ---- sweep 2: attn write + PV, barrier-free ----
    f32x4 oacc[16];
#pragma unroll
    for (int nf = 0; nf < 16; ++nf) oacc[nf] = (f32x4){0.f,0.f,0.f,0.f};

    for (int jt = wid; jt < numJT; jt += 4) {
        const short8* kp = (const short8*)(kf + (((size_t)b * 256 + jt * 4) * 8) * 512);
        f32x4 a[4];
#pragma unroll
        for (int c = 0; c < 4; ++c) a[c] = (f32x4){0.f,0.f,0.f,0.f};
#pragma unroll
        for (int kc = 0; kc < 8; ++kc)
#pragma unroll
            for (int c = 0; c < 4; ++c)
                a[c] = mfma_k32(kp[(c * 8 + kc) * 64 + lane], q8[kc], a[c]);

        s16x4 pk[4];
#pragma unroll
        for (int c = 0; c < 4; ++c) {
            f32x4 p;
#pragma unroll
            for (int r = 0; r < 4; ++r) {
                int j = jt * 64 + 16 * c + 4 * lg + r;
                p[r] = (j <= irow) ? __expf(a[c][r] * 0.0625f) * inv : 0.f;
            }
            __builtin_nontemporal_store(p,
                (f32x4*)(attnO + (size_t)irow * T_DIM + jt * 64 + 16 * c + 4 * lg));
            union { u16 u[4]; s16x4 v; } t;
#pragma unroll
            for (int r = 0; r < 4; ++r) t.u[r] = f2bf(p[r]);
            pk[c] = t.v;
        }
#pragma unroll
        for (int nf = 0; nf < 16; ++nf) {
            const s16x4* vp = (const s16x4*)(vfw +
                ((((size_t)b * 64 + jt) * 16 + nf) * 4) * 256);
#pragma unroll
            for (int c = 0; c < 4; ++c)
                oacc[nf] = mfma_k16(pk[c], vp[c * 64 + lane], oacc[nf]);
        }
    }

    // ---- combine wave-partial O via LDS (sequential waves) ----
    for (int w = 0; w < 4; ++w) {
        if (wid == w) {
#pragma unroll
            for (int nf = 0; nf < 16; ++nf)
#pragma unroll
                for (int r = 0; r < 4; ++r) {
                    int row = 4 * lg + r, d = 16 * nf + lr;
                    if (w == 0) O_sm[row * 264 + d] = oacc[nf][r];
                    else        O_sm[row * 264 + d] += oacc[nf][r];
                }
        }
        __syncthreads();
    }
    // store O -> results[t][b][d]
#pragma unroll
    for (int u = 0; u < 4; ++u) {
        int ix = tid + 256 * u;             // 0..1023
        int row = ix >> 6, c = ix & 63;     // 16 rows x 64 f32x4 chunks
        f32x4 v = *(const f32x4*)(O_sm + row * 264 + c * 4);
        __builtin_nontemporal_store(v, (f32x4*)(out + ((size_t)(i0 + row) * B_DIM + b) * 256 + c * 4));
    }

    // zero-fill strict upper triangle beyond computed tiles
    const int z0 = numJT * 64;
    if (z0 < T_DIM) {
        const int n4 = (T_DIM - z0) >> 2;
        for (int rr = 0; rr < 16; ++rr) {
            f32x4* rowp = (f32x4*)(attnO + (size_t)(i0 + rr) * T_DIM + z0);
            for (int c = tid; c < n4; c += 256) {
                f32x4 z = {0.f, 0.f, 0.f, 0.f};
                __builtin_nontemporal_store(z, rowp + c);
            }
        }
    }
}

// ---------------------------------------------------------------------------
extern "C" void kernel_launch(void* const* d_in, const int* in_sizes, int n_in,
                              void* d_out, int out_size, void* d_ws, size_t ws_size,
                              hipStream_t stream) {
    (void)in_sizes; (void)n_in; (void)out_size; (void)ws_size;
    const float* X  = (const float*)d_in[0];
    const float* Wq = (const float*)d_in[1];
    const float* Wk = (const float*)d_in[2];
    const float* Wv = (const float*)d_in[3];
    float* out = (float*)d_out;

    char* ws = (char*)d_ws;
    u16* qf  = (u16*)(ws);                                  // 8 MB
    u16* kf  = (u16*)(ws + (size_t)8  * 1024 * 1024);       // 8 MB
    u16* vfw = (u16*)(ws + (size_t)16 * 1024 * 1024);       // 8 MB
    u16* wT  = (u16*)(ws + (size_t)24 * 1024 * 1024);       // 384 KB

    wtrans_kernel<<<dim3(768), dim3(256), 0, stream>>>(Wq, Wk, Wv, wT);
    proj_kernel<<<dim3(1024), dim3(256), 0, stream>>>(X, wT, qf, kf, vfw);
    attn_kernel<<<dim3(1024), dim3(256), 0, stream>>>(qf, kf, vfw, out);
}

// Round 9
// 314.009 us; speedup vs baseline: 4.3939x; 1.4327x over previous
//
#include <hip/hip_runtime.h>
#include <hip/hip_bf16.h>

#define T_DIM 4096
#define B_DIM 4

typedef unsigned short u16;
typedef __attribute__((ext_vector_type(4))) short s16x4;
typedef __attribute__((ext_vector_type(8))) short short8;
typedef __attribute__((ext_vector_type(8))) __bf16 bf16x8;
typedef __attribute__((ext_vector_type(4))) float f32x4;

static __device__ __forceinline__ u16 f2bf(float f) {
    union { float f; unsigned int u; } v; v.f = f;
    unsigned int u = v.u;
    u += 0x7FFFu + ((u >> 16) & 1u);   // RNE
    return (u16)(u >> 16);
}

static __device__ __forceinline__ f32x4 mfma_k32(short8 a, short8 b, f32x4 c) {
    return __builtin_amdgcn_mfma_f32_16x16x32_bf16(
        __builtin_bit_cast(bf16x8, a), __builtin_bit_cast(bf16x8, b), c, 0, 0, 0);
}
static __device__ __forceinline__ f32x4 mfma_k16(s16x4 a, s16x4 b, f32x4 c) {
    return __builtin_amdgcn_mfma_f32_16x16x16bf16_1k(a, b, c, 0, 0, 0);
}

// ---------------------------------------------------------------------------
// Kernel 0: transpose + convert weights to bf16 W^T[n][k]
// ---------------------------------------------------------------------------
__global__ __launch_bounds__(256) void wtrans_kernel(
    const float* __restrict__ Wq, const float* __restrict__ Wk,
    const float* __restrict__ Wv, u16* __restrict__ wT) {
    int idx = blockIdx.x * 256 + threadIdx.x;
    int w   = idx >> 16;
    int rem = idx & 65535;
    int k   = rem >> 8;
    int n   = rem & 255;
    const float* W = (w == 0) ? Wq : (w == 1) ? Wk : Wv;
    wT[w * 65536 + n * 256 + k] = f2bf(W[k * 256 + n]);
}

// ---------------------------------------------------------------------------
// Kernel 1: projection GEMM -> FRAGMENT-PACKED outputs.
//  qf/kf (u16): [b][tile=t/16][kc=0..7][lane][e=0..7]
//      = P[b][tile*16 + (lane&15)][kc*32 + (lane>>4)*8 + e]
//  vf  (u16): [b][jt=t/64][nf=0..15][cc=0..1][lane][e=0..7]
//      = V[b][jt*64 + 16*(2cc + e/4) + 4*(lane>>4) + (e&3)][nf*16 + (lane&15)]
//  (one short8 V load now feeds TWO k16 c-slices: e<4 -> c=2cc, e>=4 -> c=2cc+1)
// ---------------------------------------------------------------------------
__global__ __launch_bounds__(256, 4) void proj_kernel(
    const float* __restrict__ X, const u16* __restrict__ wT,
    u16* __restrict__ qf, u16* __restrict__ kf, u16* __restrict__ vfw) {
    const int r0  = blockIdx.x * 16;
    const int wid = threadIdx.x >> 6, lane = threadIdx.x & 63;
    const int lr  = lane & 15, lg = lane >> 4;

    short8 af[8];
    const float* xrow = X + (size_t)(r0 + lr) * 256 + lg * 8;
#pragma unroll
    for (int kc = 0; kc < 8; ++kc) {
        f32x4 xa = *(const f32x4*)(xrow + kc * 32);
        f32x4 xb = *(const f32x4*)(xrow + kc * 32 + 4);
        union { u16 u[8]; short8 v; } t;
#pragma unroll
        for (int e = 0; e < 4; ++e) { t.u[e] = f2bf(xa[e]); t.u[4 + e] = f2bf(xb[e]); }
        af[kc] = t.v;
    }

    for (int w = 0; w < 3; ++w) {
        f32x4 acc[4];
#pragma unroll
        for (int nf = 0; nf < 4; ++nf) acc[nf] = (f32x4){0.f,0.f,0.f,0.f};
        const u16* wbase = wT + w * 65536 + (size_t)(16 * (4 * wid) + lr) * 256 + lg * 8;
#pragma unroll
        for (int kc = 0; kc < 8; ++kc)
#pragma unroll
            for (int nf = 0; nf < 4; ++nf) {
                short8 bfv = *(const short8*)(wbase + nf * 16 * 256 + kc * 32);
                acc[nf] = mfma_k32(af[kc], bfv, acc[nf]);
            }
#pragma unroll
        for (int nf = 0; nf < 4; ++nf)
#pragma unroll
            for (int r = 0; r < 4; ++r) {
                int rg = r0 + 4 * lg + r;
                int t  = rg >> 2, bb = rg & 3;           // X rows are (t, b)
                int d  = 16 * (4 * wid + nf) + lr;
                u16 val = f2bf(acc[nf][r]);
                if (w < 2) {
                    int tile = t >> 4, lrq = t & 15;
                    int kc = d >> 5, lgq = (d >> 3) & 3, e = d & 7;
                    size_t idx = ((((size_t)bb * 256 + tile) * 8 + kc) * 64
                                  + lrq + 16 * lgq) * 8 + e;
                    if (w == 0) qf[idx] = val; else kf[idx] = val;
                } else {
                    int jt = t >> 6, c = (t >> 4) & 3;
                    int cc = c >> 1, eh = c & 1;
                    int lgv = (t >> 2) & 3, el = t & 3, e = eh * 4 + el;
                    int nfv = d >> 4, lrv = d & 15;
                    size_t idx = (((((size_t)bb * 64 + jt) * 16 + nfv) * 2 + cc) * 64
                                  + lrv + 16 * lgv) * 8 + e;
                    vfw[idx] = val;
                }
            }
    }
}

// ---------------------------------------------------------------------------
// Kernel 2: fused causal attention. Grid 512 x 512thr (8 waves) = exactly
// 2 blocks/CU resident, uniform work: block = i_tile pair (p, 255-p), two
// sequential phases. Within a phase: j-tiles strided across 8 waves, each
// wave 4 independent QK chains, lane-local P, barrier-free j-loop.
// ---------------------------------------------------------------------------
__global__ __launch_bounds__(512, 4) void attn_kernel(
    const u16* __restrict__ qf, const u16* __restrict__ kf,
    const u16* __restrict__ vfw, float* __restrict__ out) {
    __shared__ float l_sm[16];
    __shared__ float O_sm[16 * 264];

    const int blk = blockIdx.x;
    const int xcd = blk & 7, idx = blk >> 3;     // idx 0..63
    const int b = xcd >> 1, par = xcd & 1;       // one b per XCD pair
    const int pair = 2 * idx + par;              // 0..127

    const int tid = threadIdx.x;
    const int wid = tid >> 6, lane = tid & 63;
    const int lr = lane & 15, lg = lane >> 4;

    float* attnO = out + (size_t)T_DIM * B_DIM * 256 + (size_t)b * T_DIM * T_DIM;

    for (int phase = 0; phase < 2; ++phase) {
        const int i_tile = phase ? (255 - pair) : pair;
        const int i0 = i_tile * 16;
        const int irow = i0 + lr;
        const int numJT = i_tile / 4 + 1;

        __syncthreads();                 // previous phase fully done with LDS
        if (tid < 16) l_sm[tid] = 0.f;
        __syncthreads();

        // Q fragments (lane-contiguous), shared by all waves
        short8 q8[8];
        const short8* qp = (const short8*)(qf + (((size_t)b * 256 + i_tile) * 8) * 512);
#pragma unroll
        for (int kc = 0; kc < 8; ++kc) q8[kc] = qp[kc * 64 + lane];

        // ---- sweep 1: partial row sums of exp(S) ----
        float rs = 0.f;
        for (int jt = wid; jt < numJT; jt += 8) {
            const short8* kp = (const short8*)(kf + (((size_t)b * 256 + jt * 4) * 8) * 512);
            f32x4 a[4];
#pragma unroll
            for (int c = 0; c < 4; ++c) a[c] = (f32x4){0.f,0.f,0.f,0.f};
#pragma unroll
            for (int kc = 0; kc < 8; ++kc)
#pragma unroll
                for (int c = 0; c < 4; ++c)
                    a[c] = mfma_k32(kp[(c * 8 + kc) * 64 + lane], q8[kc], a[c]);
#pragma unroll
            for (int c = 0; c < 4; ++c)
#pragma unroll
                for (int r = 0; r < 4; ++r) {
                    int j = jt * 64 + 16 * c + 4 * lg + r;
                    rs += (j <= irow) ? __expf(a[c][r] * 0.0625f) : 0.f;
                }
        }
        rs += __shfl_xor(rs, 16, 64);
        rs += __shfl_xor(rs, 32, 64);
        if (lane < 16) atomicAdd(&l_sm[lr], rs);
        __syncthreads();
        const float inv = 1.0f / l_sm[lr];

        // ---- sweep 2: attn write + PV, barrier-free ----
        f32x4 oacc[16];
#pragma unroll
        for (int nf = 0; nf < 16; ++nf) oacc[nf] = (f32x4){0.f,0.f,0.f,0.f};

        for (int jt = wid; jt < numJT; jt += 8) {
            const short8* kp = (const short8*)(kf + (((size_t)b * 256 + jt * 4) * 8) * 512);
            f32x4 a[4];
#pragma unroll
            for (int c = 0; c < 4; ++c) a[c] = (f32x4){0.f,0.f,0.f,0.f};
#pragma unroll
            for (int kc = 0; kc < 8; ++kc)
#pragma unroll
                for (int c = 0; c < 4; ++c)
                    a[c] = mfma_k32(kp[(c * 8 + kc) * 64 + lane], q8[kc], a[c]);

            s16x4 pk[4];
#pragma unroll
            for (int c = 0; c < 4; ++c) {
#pragma unroll
                for (int r = 0; r < 4; ++r) {
                    int j = jt * 64 + 16 * c + 4 * lg + r;
                    a[c][r] = (j <= irow) ? __expf(a[c][r] * 0.0625f) * inv : 0.f;
                }
                __builtin_nontemporal_store(a[c],
                    (f32x4*)(attnO + (size_t)irow * T_DIM + jt * 64 + 16 * c + 4 * lg));
                union { u16 u[4]; s16x4 v; } t;
#pragma unroll
                for (int r = 0; r < 4; ++r) t.u[r] = f2bf(a[c][r]);
                pk[c] = t.v;
            }

            const u16* vb = vfw + (((size_t)b * 64 + jt) * 16) * 1024;
#pragma unroll
            for (int nf = 0; nf < 16; ++nf) {
                const short8* vp = (const short8*)(vb + nf * 1024);
                short8 v0 = vp[lane];
                short8 v1 = vp[64 + lane];
                oacc[nf] = mfma_k16(pk[0], __builtin_shufflevector(v0, v0, 0,1,2,3), oacc[nf]);
                oacc[nf] = mfma_k16(pk[1], __builtin_shufflevector(v0, v0, 4,5,6,7), oacc[nf]);
                oacc[nf] = mfma_k16(pk[2], __builtin_shufflevector(v1, v1, 0,1,2,3), oacc[nf]);
                oacc[nf] = mfma_k16(pk[3], __builtin_shufflevector(v1, v1, 4,5,6,7), oacc[nf]);
            }
        }

        // ---- combine wave-partial O via LDS (sequential waves) ----
        for (int w = 0; w < 8; ++w) {
            if (wid == w) {
#pragma unroll
                for (int nf = 0; nf < 16; ++nf)
#pragma unroll
                    for (int r = 0; r < 4; ++r) {
                        int row = 4 * lg + r, d = 16 * nf + lr;
                        if (w == 0) O_sm[row * 264 + d] = oacc[nf][r];
                        else        O_sm[row * 264 + d] += oacc[nf][r];
                    }
            }
            __syncthreads();
        }
        // store O -> results[t][b][d]
#pragma unroll
        for (int u = 0; u < 2; ++u) {
            int ix = tid + 512 * u;             // 0..1023
            int row = ix >> 6, c = ix & 63;     // 16 rows x 64 f32x4 chunks
            f32x4 v = *(const f32x4*)(O_sm + row * 264 + c * 4);
            __builtin_nontemporal_store(v,
                (f32x4*)(out + ((size_t)(i0 + row) * B_DIM + b) * 256 + c * 4));
        }

        // zero-fill strict upper triangle beyond computed tiles
        const int z0 = numJT * 64;
        if (z0 < T_DIM) {
            const int n4 = (T_DIM - z0) >> 2;
            for (int rr = 0; rr < 16; ++rr) {
                f32x4* rowp = (f32x4*)(attnO + (size_t)(i0 + rr) * T_DIM + z0);
                for (int c = tid; c < n4; c += 512) {
                    f32x4 z = {0.f, 0.f, 0.f, 0.f};
                    __builtin_nontemporal_store(z, rowp + c);
                }
            }
        }
    }
}

// ---------------------------------------------------------------------------
extern "C" void kernel_launch(void* const* d_in, const int* in_sizes, int n_in,
                              void* d_out, int out_size, void* d_ws, size_t ws_size,
                              hipStream_t stream) {
    (void)in_sizes; (void)n_in; (void)out_size; (void)ws_size;
    const float* X  = (const float*)d_in[0];
    const float* Wq = (const float*)d_in[1];
    const float* Wk = (const float*)d_in[2];
    const float* Wv = (const float*)d_in[3];
    float* out = (float*)d_out;

    char* ws = (char*)d_ws;
    u16* qf  = (u16*)(ws);                                  // 8 MB
    u16* kf  = (u16*)(ws + (size_t)8  * 1024 * 1024);       // 8 MB
    u16* vfw = (u16*)(ws + (size_t)16 * 1024 * 1024);       // 8 MB
    u16* wT  = (u16*)(ws + (size_t)24 * 1024 * 1024);       // 384 KB

    wtrans_kernel<<<dim3(768), dim3(256), 0, stream>>>(Wq, Wk, Wv, wT);
    proj_kernel<<<dim3(1024), dim3(256), 0, stream>>>(X, wT, qf, kf, vfw);
    attn_kernel<<<dim3(512), dim3(512), 0, stream>>>(qf, kf, vfw, out);
}

// Round 10
// 312.137 us; speedup vs baseline: 4.4203x; 1.0060x over previous
//
#include <hip/hip_runtime.h>
#include <hip/hip_bf16.h>

#define T_DIM 4096
#define B_DIM 4

typedef unsigned short u16;
typedef __attribute__((ext_vector_type(4))) short s16x4;
typedef __attribute__((ext_vector_type(8))) short short8;
typedef __attribute__((ext_vector_type(8))) __bf16 bf16x8;
typedef __attribute__((ext_vector_type(4))) float f32x4;

static __device__ __forceinline__ u16 f2bf(float f) {
    union { float f; unsigned int u; } v; v.f = f;
    unsigned int u = v.u;
    u += 0x7FFFu + ((u >> 16) & 1u);   // RNE
    return (u16)(u >> 16);
}

static __device__ __forceinline__ f32x4 mfma_k32(short8 a, short8 b, f32x4 c) {
    return __builtin_amdgcn_mfma_f32_16x16x32_bf16(
        __builtin_bit_cast(bf16x8, a), __builtin_bit_cast(bf16x8, b), c, 0, 0, 0);
}
static __device__ __forceinline__ f32x4 mfma_k16(s16x4 a, s16x4 b, f32x4 c) {
    return __builtin_amdgcn_mfma_f32_16x16x16bf16_1k(a, b, c, 0, 0, 0);
}

// ---------------------------------------------------------------------------
// Kernel 0: transpose + convert weights to bf16 W^T[n][k]
// ---------------------------------------------------------------------------
__global__ __launch_bounds__(256) void wtrans_kernel(
    const float* __restrict__ Wq, const float* __restrict__ Wk,
    const float* __restrict__ Wv, u16* __restrict__ wT) {
    int idx = blockIdx.x * 256 + threadIdx.x;
    int w   = idx >> 16;
    int rem = idx & 65535;
    int k   = rem >> 8;
    int n   = rem & 255;
    const float* W = (w == 0) ? Wq : (w == 1) ? Wk : Wv;
    wT[w * 65536 + n * 256 + k] = f2bf(W[k * 256 + n]);
}

// ---------------------------------------------------------------------------
// Kernel 1: projection GEMM -> FRAGMENT-PACKED outputs.
//  qf/kf (u16): [b][tile=t/16][kc=0..7][lane][e=0..7]
//      = P[b][tile*16 + (lane&15)][kc*32 + (lane>>4)*8 + e]
//  vf  (u16): [b][jt=t/64][nf=0..15][cc=0..1][lane][e=0..7]
//      = V[b][jt*64 + 16*(2cc + e/4) + 4*(lane>>4) + (e&3)][nf*16 + (lane&15)]
//  (one short8 V load feeds TWO k16 c-slices: e<4 -> c=2cc, e>=4 -> c=2cc+1)
// ---------------------------------------------------------------------------
__global__ __launch_bounds__(256, 4) void proj_kernel(
    const float* __restrict__ X, const u16* __restrict__ wT,
    u16* __restrict__ qf, u16* __restrict__ kf, u16* __restrict__ vfw) {
    const int r0  = blockIdx.x * 16;
    const int wid = threadIdx.x >> 6, lane = threadIdx.x & 63;
    const int lr  = lane & 15, lg = lane >> 4;

    short8 af[8];
    const float* xrow = X + (size_t)(r0 + lr) * 256 + lg * 8;
#pragma unroll
    for (int kc = 0; kc < 8; ++kc) {
        f32x4 xa = *(const f32x4*)(xrow + kc * 32);
        f32x4 xb = *(const f32x4*)(xrow + kc * 32 + 4);
        union { u16 u[8]; short8 v; } t;
#pragma unroll
        for (int e = 0; e < 4; ++e) { t.u[e] = f2bf(xa[e]); t.u[4 + e] = f2bf(xb[e]); }
        af[kc] = t.v;
    }

    for (int w = 0; w < 3; ++w) {
        f32x4 acc[4];
#pragma unroll
        for (int nf = 0; nf < 4; ++nf) acc[nf] = (f32x4){0.f,0.f,0.f,0.f};
        const u16* wbase = wT + w * 65536 + (size_t)(16 * (4 * wid) + lr) * 256 + lg * 8;
#pragma unroll
        for (int kc = 0; kc < 8; ++kc)
#pragma unroll
            for (int nf = 0; nf < 4; ++nf) {
                short8 bfv = *(const short8*)(wbase + nf * 16 * 256 + kc * 32);
                acc[nf] = mfma_k32(af[kc], bfv, acc[nf]);
            }
#pragma unroll
        for (int nf = 0; nf < 4; ++nf)
#pragma unroll
            for (int r = 0; r < 4; ++r) {
                int rg = r0 + 4 * lg + r;
                int t  = rg >> 2, bb = rg & 3;           // X rows are (t, b)
                int d  = 16 * (4 * wid + nf) + lr;
                u16 val = f2bf(acc[nf][r]);
                if (w < 2) {
                    int tile = t >> 4, lrq = t & 15;
                    int kc = d >> 5, lgq = (d >> 3) & 3, e = d & 7;
                    size_t idx = ((((size_t)bb * 256 + tile) * 8 + kc) * 64
                                  + lrq + 16 * lgq) * 8 + e;
                    if (w == 0) qf[idx] = val; else kf[idx] = val;
                } else {
                    int jt = t >> 6, c = (t >> 4) & 3;
                    int cc = c >> 1, eh = c & 1;
                    int lgv = (t >> 2) & 3, el = t & 3, e = eh * 4 + el;
                    int nfv = d >> 4, lrv = d & 15;
                    size_t idx = (((((size_t)bb * 64 + jt) * 16 + nfv) * 2 + cc) * 64
                                  + lrv + 16 * lgv) * 8 + e;
                    vfw[idx] = val;
                }
            }
    }
}

// ---------------------------------------------------------------------------
// Kernel 2: fused causal attention. Grid 512 x 512thr (8 waves) = exactly
// 2 blocks/CU resident, uniform work: block = i_tile pair (p, 255-p), two
// sequential phases. Within a phase: j-tiles strided across 8 waves, each
// wave 4 independent QK chains, lane-local P, barrier-free j-loop.
// NOTE: no min-waves launch-bounds arg — (512,4) forced VGPR=64 and ~375 MB
// of spill traffic (R1, R7). Allocator needs ~160 VGPR here.
// ---------------------------------------------------------------------------
__global__ __launch_bounds__(512) void attn_kernel(
    const u16* __restrict__ qf, const u16* __restrict__ kf,
    const u16* __restrict__ vfw, float* __restrict__ out) {
    __shared__ float l_sm[16];
    __shared__ float O_sm[16 * 264];

    const int blk = blockIdx.x;
    const int xcd = blk & 7, idx = blk >> 3;     // idx 0..63
    const int b = xcd >> 1, par = xcd & 1;       // one b per XCD pair
    const int pair = 2 * idx + par;              // 0..127

    const int tid = threadIdx.x;
    const int wid = tid >> 6, lane = tid & 63;
    const int lr = lane & 15, lg = lane >> 4;

    float* attnO = out + (size_t)T_DIM * B_DIM * 256 + (size_t)b * T_DIM * T_DIM;

    for (int phase = 0; phase < 2; ++phase) {
        const int i_tile = phase ? (255 - pair) : pair;
        const int i0 = i_tile * 16;
        const int irow = i0 + lr;
        const int numJT = i_tile / 4 + 1;

        __syncthreads();                 // previous phase fully done with LDS
        if (tid < 16) l_sm[tid] = 0.f;
        __syncthreads();

        // Q fragments (lane-contiguous), shared by all waves
        short8 q8[8];
        const short8* qp = (const short8*)(qf + (((size_t)b * 256 + i_tile) * 8) * 512);
#pragma unroll
        for (int kc = 0; kc < 8; ++kc) q8[kc] = qp[kc * 64 + lane];

        // ---- sweep 1: partial row sums of exp(S) ----
        float rs = 0.f;
        for (int jt = wid; jt < numJT; jt += 8) {
            const short8* kp = (const short8*)(kf + (((size_t)b * 256 + jt * 4) * 8) * 512);
            f32x4 a[4];
#pragma unroll
            for (int c = 0; c < 4; ++c) a[c] = (f32x4){0.f,0.f,0.f,0.f};
#pragma unroll
            for (int kc = 0; kc < 8; ++kc)
#pragma unroll
                for (int c = 0; c < 4; ++c)
                    a[c] = mfma_k32(kp[(c * 8 + kc) * 64 + lane], q8[kc], a[c]);
#pragma unroll
            for (int c = 0; c < 4; ++c)
#pragma unroll
                for (int r = 0; r < 4; ++r) {
                    int j = jt * 64 + 16 * c + 4 * lg + r;
                    rs += (j <= irow) ? __expf(a[c][r] * 0.0625f) : 0.f;
                }
        }
        rs += __shfl_xor(rs, 16, 64);
        rs += __shfl_xor(rs, 32, 64);
        if (lane < 16) atomicAdd(&l_sm[lr], rs);
        __syncthreads();
        const float inv = 1.0f / l_sm[lr];

        // ---- sweep 2: attn write + PV, barrier-free ----
        f32x4 oacc[16];
#pragma unroll
        for (int nf = 0; nf < 16; ++nf) oacc[nf] = (f32x4){0.f,0.f,0.f,0.f};

        for (int jt = wid; jt < numJT; jt += 8) {
            const short8* kp = (const short8*)(kf + (((size_t)b * 256 + jt * 4) * 8) * 512);
            f32x4 a[4];
#pragma unroll
            for (int c = 0; c < 4; ++c) a[c] = (f32x4){0.f,0.f,0.f,0.f};
#pragma unroll
            for (int kc = 0; kc < 8; ++kc)
#pragma unroll
                for (int c = 0; c < 4; ++c)
                    a[c] = mfma_k32(kp[(c * 8 + kc) * 64 + lane], q8[kc], a[c]);

            s16x4 pk[4];
#pragma unroll
            for (int c = 0; c < 4; ++c) {
#pragma unroll
                for (int r = 0; r < 4; ++r) {
                    int j = jt * 64 + 16 * c + 4 * lg + r;
                    a[c][r] = (j <= irow) ? __expf(a[c][r] * 0.0625f) * inv : 0.f;
                }
                __builtin_nontemporal_store(a[c],
                    (f32x4*)(attnO + (size_t)irow * T_DIM + jt * 64 + 16 * c + 4 * lg));
                union { u16 u[4]; s16x4 v; } t;
#pragma unroll
                for (int r = 0; r < 4; ++r) t.u[r] = f2bf(a[c][r]);
                pk[c] = t.v;
            }

            const u16* vb = vfw + (((size_t)b * 64 + jt) * 16) * 1024;
#pragma unroll
            for (int nf = 0; nf < 16; ++nf) {
                const short8* vp = (const short8*)(vb + nf * 1024);
                short8 v0 = vp[lane];
                short8 v1 = vp[64 + lane];
                oacc[nf] = mfma_k16(pk[0], __builtin_shufflevector(v0, v0, 0,1,2,3), oacc[nf]);
                oacc[nf] = mfma_k16(pk[1], __builtin_shufflevector(v0, v0, 4,5,6,7), oacc[nf]);
                oacc[nf] = mfma_k16(pk[2], __builtin_shufflevector(v1, v1, 0,1,2,3), oacc[nf]);
                oacc[nf] = mfma_k16(pk[3], __builtin_shufflevector(v1, v1, 4,5,6,7), oacc[nf]);
            }
        }

        // ---- combine wave-partial O via LDS (sequential waves) ----
        for (int w = 0; w < 8; ++w) {
            if (wid == w) {
#pragma unroll
                for (int nf = 0; nf < 16; ++nf)
#pragma unroll
                    for (int r = 0; r < 4; ++r) {
                        int row = 4 * lg + r, d = 16 * nf + lr;
                        if (w == 0) O_sm[row * 264 + d] = oacc[nf][r];
                        else        O_sm[row * 264 + d] += oacc[nf][r];
                    }
            }
            __syncthreads();
        }
        // store O -> results[t][b][d]
#pragma unroll
        for (int u = 0; u < 2; ++u) {
            int ix = tid + 512 * u;             // 0..1023
            int row = ix >> 6, c = ix & 63;     // 16 rows x 64 f32x4 chunks
            f32x4 v = *(const f32x4*)(O_sm + row * 264 + c * 4);
            __builtin_nontemporal_store(v,
                (f32x4*)(out + ((size_t)(i0 + row) * B_DIM + b) * 256 + c * 4));
        }

        // zero-fill strict upper triangle beyond computed tiles
        const int z0 = numJT * 64;
        if (z0 < T_DIM) {
            const int n4 = (T_DIM - z0) >> 2;
            for (int rr = 0; rr < 16; ++rr) {
                f32x4* rowp = (f32x4*)(attnO + (size_t)(i0 + rr) * T_DIM + z0);
                for (int c = tid; c < n4; c += 512) {
                    f32x4 z = {0.f, 0.f, 0.f, 0.f};
                    __builtin_nontemporal_store(z, rowp + c);
                }
            }
        }
    }
}

// ---------------------------------------------------------------------------
extern "C" void kernel_launch(void* const* d_in, const int* in_sizes, int n_in,
                              void* d_out, int out_size, void* d_ws, size_t ws_size,
                              hipStream_t stream) {
    (void)in_sizes; (void)n_in; (void)out_size; (void)ws_size;
    const float* X  = (const float*)d_in[0];
    const float* Wq = (const float*)d_in[1];
    const float* Wk = (const float*)d_in[2];
    const float* Wv = (const float*)d_in[3];
    float* out = (float*)d_out;

    char* ws = (char*)d_ws;
    u16* qf  = (u16*)(ws);                                  // 8 MB
    u16* kf  = (u16*)(ws + (size_t)8  * 1024 * 1024);       // 8 MB
    u16* vfw = (u16*)(ws + (size_t)16 * 1024 * 1024);       // 8 MB
    u16* wT  = (u16*)(ws + (size_t)24 * 1024 * 1024);       // 384 KB

    wtrans_kernel<<<dim3(768), dim3(256), 0, stream>>>(Wq, Wk, Wv, wT);
    proj_kernel<<<dim3(1024), dim3(256), 0, stream>>>(X, wT, qf, kf, vfw);
    attn_kernel<<<dim3(512), dim3(512), 0, stream>>>(qf, kf, vfw, out);
}

// Round 11
// 258.107 us; speedup vs baseline: 5.3456x; 1.2093x over previous
//
#include <hip/hip_runtime.h>
#include <hip/hip_bf16.h>

#define T_DIM 4096
#define B_DIM 4

typedef unsigned short u16;
typedef __attribute__((ext_vector_type(4))) short s16x4;
typedef __attribute__((ext_vector_type(8))) short short8;
typedef __attribute__((ext_vector_type(8))) __bf16 bf16x8;
typedef __attribute__((ext_vector_type(4))) float f32x4;

static __device__ __forceinline__ u16 f2bf(float f) {
    union { float f; unsigned int u; } v; v.f = f;
    unsigned int u = v.u;
    u += 0x7FFFu + ((u >> 16) & 1u);   // RNE
    return (u16)(u >> 16);
}

static __device__ __forceinline__ f32x4 mfma_k32(short8 a, short8 b, f32x4 c) {
    return __builtin_amdgcn_mfma_f32_16x16x32_bf16(
        __builtin_bit_cast(bf16x8, a), __builtin_bit_cast(bf16x8, b), c, 0, 0, 0);
}
static __device__ __forceinline__ f32x4 mfma_k16(s16x4 a, s16x4 b, f32x4 c) {
    return __builtin_amdgcn_mfma_f32_16x16x16bf16_1k(a, b, c, 0, 0, 0);
}

// ---------------------------------------------------------------------------
// Kernel 0: transpose + convert weights to bf16 W^T[n][k]
// ---------------------------------------------------------------------------
__global__ __launch_bounds__(256) void wtrans_kernel(
    const float* __restrict__ Wq, const float* __restrict__ Wk,
    const float* __restrict__ Wv, u16* __restrict__ wT) {
    int idx = blockIdx.x * 256 + threadIdx.x;
    int w   = idx >> 16;
    int rem = idx & 65535;
    int k   = rem >> 8;
    int n   = rem & 255;
    const float* W = (w == 0) ? Wq : (w == 1) ? Wk : Wv;
    wT[w * 65536 + n * 256 + k] = f2bf(W[k * 256 + n]);
}

// ---------------------------------------------------------------------------
// Kernel 1: projection GEMM -> FRAGMENT-PACKED outputs (validated R4-R9).
//  qf/kf (u16): [b][tile=t/16][kc=0..7][lane][e=0..7]
//      = P[b][tile*16 + (lane&15)][kc*32 + (lane>>4)*8 + e]
//  vf  (u16): [b][jt=t/64][nf=0..15][cc=0..1][lane][e=0..7]
//      = V[b][jt*64 + 16*(2cc + e/4) + 4*(lane>>4) + (e&3)][nf*16 + (lane&15)]
// ---------------------------------------------------------------------------
__global__ __launch_bounds__(256, 4) void proj_kernel(
    const float* __restrict__ X, const u16* __restrict__ wT,
    u16* __restrict__ qf, u16* __restrict__ kf, u16* __restrict__ vfw) {
    const int r0  = blockIdx.x * 16;
    const int wid = threadIdx.x >> 6, lane = threadIdx.x & 63;
    const int lr  = lane & 15, lg = lane >> 4;

    short8 af[8];
    const float* xrow = X + (size_t)(r0 + lr) * 256 + lg * 8;
#pragma unroll
    for (int kc = 0; kc < 8; ++kc) {
        f32x4 xa = *(const f32x4*)(xrow + kc * 32);
        f32x4 xb = *(const f32x4*)(xrow + kc * 32 + 4);
        union { u16 u[8]; short8 v; } t;
#pragma unroll
        for (int e = 0; e < 4; ++e) { t.u[e] = f2bf(xa[e]); t.u[4 + e] = f2bf(xb[e]); }
        af[kc] = t.v;
    }

    for (int w = 0; w < 3; ++w) {
        f32x4 acc[4];
#pragma unroll
        for (int nf = 0; nf < 4; ++nf) acc[nf] = (f32x4){0.f,0.f,0.f,0.f};
        const u16* wbase = wT + w * 65536 + (size_t)(16 * (4 * wid) + lr) * 256 + lg * 8;
#pragma unroll
        for (int kc = 0; kc < 8; ++kc)
#pragma unroll
            for (int nf = 0; nf < 4; ++nf) {
                short8 bfv = *(const short8*)(wbase + nf * 16 * 256 + kc * 32);
                acc[nf] = mfma_k32(af[kc], bfv, acc[nf]);
            }
#pragma unroll
        for (int nf = 0; nf < 4; ++nf)
#pragma unroll
            for (int r = 0; r < 4; ++r) {
                int rg = r0 + 4 * lg + r;
                int t  = rg >> 2, bb = rg & 3;           // X rows are (t, b)
                int d  = 16 * (4 * wid + nf) + lr;
                u16 val = f2bf(acc[nf][r]);
                if (w < 2) {
                    int tile = t >> 4, lrq = t & 15;
                    int kc = d >> 5, lgq = (d >> 3) & 3, e = d & 7;
                    size_t idx = ((((size_t)bb * 256 + tile) * 8 + kc) * 64
                                  + lrq + 16 * lgq) * 8 + e;
                    if (w == 0) qf[idx] = val; else kf[idx] = val;
                } else {
                    int jt = t >> 6, c = (t >> 4) & 3;
                    int cc = c >> 1, eh = c & 1;
                    int lgv = (t >> 2) & 3, el = t & 3, e = eh * 4 + el;
                    int nfv = d >> 4, lrv = d & 15;
                    size_t idx = (((((size_t)bb * 64 + jt) * 16 + nfv) * 2 + cc) * 64
                                  + lrv + 16 * lgv) * 8 + e;
                    vfw[idx] = val;
                }
            }
    }
}

// ---------------------------------------------------------------------------
// Kernel 2: fused causal attention, SAME-JT wave cooperation.
// Block = 32 query rows; 8 waves = (f: i-frag 0..1) x (h: 16-wide j-quarter
// 0..3). All waves walk the SAME jt sequence -> per-iter working set is one
// 64-wide K/V tile (64 KB), L1-deduped across waves. Blocks paired (p,127-p)
// for uniform work; grid 256 = 1 block/CU. Barrier-free j-loop.
// ---------------------------------------------------------------------------
__global__ __launch_bounds__(512) void attn_kernel(
    const u16* __restrict__ qf, const u16* __restrict__ kf,
    const u16* __restrict__ vfw, float* __restrict__ out) {
    __shared__ float l_sm[32];
    __shared__ float O_sm[32 * 264];

    const int blk = blockIdx.x;
    const int xcd = blk & 7;                     // one b per XCD pair
    const int b = xcd >> 1, par = xcd & 1;
    const int pair = 2 * (blk >> 3) + par;       // 0..63

    const int tid = threadIdx.x;
    const int wid = tid >> 6, lane = tid & 63;
    const int f = wid >> 2, h = wid & 3;         // i-frag, j-quarter
    const int lr = lane & 15, lg = lane >> 4;

    float* attnO = out + (size_t)T_DIM * B_DIM * 256 + (size_t)b * T_DIM * T_DIM;

    for (int phase = 0; phase < 2; ++phase) {
        const int it = phase ? (127 - pair) : pair;   // i_tile (32-row), 0..127
        const int i0 = it * 32;
        const int irow = i0 + 16 * f + lr;
        const int numJT = it / 2 + 1;

        __syncthreads();                 // previous phase done with LDS
        if (tid < 32) l_sm[tid] = 0.f;
        __syncthreads();

        // Q fragments for this wave's i-frag (lane-contiguous)
        short8 q8[8];
        const short8* qp = (const short8*)(qf + (((size_t)b * 256 + it * 2 + f) * 8) * 512);
#pragma unroll
        for (int kc = 0; kc < 8; ++kc) q8[kc] = qp[kc * 64 + lane];

        // ---- sweep 1: row sums of exp(S) over this wave's j-quarter ----
        float rs = 0.f;
        for (int jt = 0; jt < numJT; ++jt) {
            const short8* kp = (const short8*)(kf + (((size_t)b * 256 + jt * 4 + h) * 8) * 512);
            f32x4 a = {0.f,0.f,0.f,0.f};
#pragma unroll
            for (int kc = 0; kc < 8; ++kc)
                a = mfma_k32(kp[kc * 64 + lane], q8[kc], a);
            const int j0 = jt * 64 + 16 * h + 4 * lg;
#pragma unroll
            for (int r = 0; r < 4; ++r)
                rs += (j0 + r <= irow) ? __expf(a[r] * 0.0625f) : 0.f;
        }
        rs += __shfl_xor(rs, 16, 64);
        rs += __shfl_xor(rs, 32, 64);
        if (lane < 16) atomicAdd(&l_sm[16 * f + lr], rs);
        __syncthreads();
        const float inv = 1.0f / l_sm[16 * f + lr];

        // ---- sweep 2: attn write + PV, barrier-free ----
        f32x4 oacc[16];
#pragma unroll
        for (int nf = 0; nf < 16; ++nf) oacc[nf] = (f32x4){0.f,0.f,0.f,0.f};

        for (int jt = 0; jt < numJT; ++jt) {
            const short8* kp = (const short8*)(kf + (((size_t)b * 256 + jt * 4 + h) * 8) * 512);
            f32x4 a = {0.f,0.f,0.f,0.f};
#pragma unroll
            for (int kc = 0; kc < 8; ++kc)
                a = mfma_k32(kp[kc * 64 + lane], q8[kc], a);

            const int j0 = jt * 64 + 16 * h + 4 * lg;
#pragma unroll
            for (int r = 0; r < 4; ++r)
                a[r] = (j0 + r <= irow) ? __expf(a[r] * 0.0625f) * inv : 0.f;
            __builtin_nontemporal_store(a,
                (f32x4*)(attnO + (size_t)irow * T_DIM + j0));

            union { u16 u[4]; s16x4 v; } t;
#pragma unroll
            for (int r = 0; r < 4; ++r) t.u[r] = f2bf(a[r]);
            const s16x4 pk = t.v;

            // V quarter h: cc = h>>1, element-half = h&1 (8B per lane)
            const u16* vb = vfw + (((size_t)b * 64 + jt) * 32 + (h >> 1)) * 512
                          + (size_t)lane * 8 + (h & 1) * 4;
#pragma unroll
            for (int nf = 0; nf < 16; ++nf) {
                s16x4 vf = *(const s16x4*)(vb + (size_t)nf * 1024);
                oacc[nf] = mfma_k16(pk, vf, oacc[nf]);
            }
        }

        // ---- combine the 4 j-quarter partials per i-frag via LDS ----
        for (int step = 0; step < 4; ++step) {
            if (h == step) {
#pragma unroll
                for (int nf = 0; nf < 16; ++nf)
#pragma unroll
                    for (int r = 0; r < 4; ++r) {
                        int row = 16 * f + 4 * lg + r, d = 16 * nf + lr;
                        if (step == 0) O_sm[row * 264 + d] = oacc[nf][r];
                        else           O_sm[row * 264 + d] += oacc[nf][r];
                    }
            }
            __syncthreads();
        }
        // store O -> results[t][b][d]
#pragma unroll
        for (int u = 0; u < 4; ++u) {
            int ix = tid + 512 * u;             // 0..2047
            int row = ix >> 6, c = ix & 63;     // 32 rows x 64 f32x4 chunks
            f32x4 v = *(const f32x4*)(O_sm + row * 264 + c * 4);
            __builtin_nontemporal_store(v,
                (f32x4*)(out + ((size_t)(i0 + row) * B_DIM + b) * 256 + c * 4));
        }

        // zero-fill strict upper triangle beyond computed tiles
        const int z0 = numJT * 64;
        if (z0 < T_DIM) {
            const int n4 = (T_DIM - z0) >> 2;
            for (int rr = 0; rr < 32; ++rr) {
                f32x4* rowp = (f32x4*)(attnO + (size_t)(i0 + rr) * T_DIM + z0);
                for (int c = tid; c < n4; c += 512) {
                    f32x4 z = {0.f, 0.f, 0.f, 0.f};
                    __builtin_nontemporal_store(z, rowp + c);
                }
            }
        }
    }
}

// ---------------------------------------------------------------------------
extern "C" void kernel_launch(void* const* d_in, const int* in_sizes, int n_in,
                              void* d_out, int out_size, void* d_ws, size_t ws_size,
                              hipStream_t stream) {
    (void)in_sizes; (void)n_in; (void)out_size; (void)ws_size;
    const float* X  = (const float*)d_in[0];
    const float* Wq = (const float*)d_in[1];
    const float* Wk = (const float*)d_in[2];
    const float* Wv = (const float*)d_in[3];
    float* out = (float*)d_out;

    char* ws = (char*)d_ws;
    u16* qf  = (u16*)(ws);                                  // 8 MB
    u16* kf  = (u16*)(ws + (size_t)8  * 1024 * 1024);       // 8 MB
    u16* vfw = (u16*)(ws + (size_t)16 * 1024 * 1024);       // 8 MB
    u16* wT  = (u16*)(ws + (size_t)24 * 1024 * 1024);       // 384 KB

    wtrans_kernel<<<dim3(768), dim3(256), 0, stream>>>(Wq, Wk, Wv, wT);
    proj_kernel<<<dim3(1024), dim3(256), 0, stream>>>(X, wT, qf, kf, vfw);
    attn_kernel<<<dim3(256), dim3(512), 0, stream>>>(qf, kf, vfw, out);
}